// Round 9
// baseline (155.541 us; speedup 1.0000x reference)
//
#include <hip/hip_runtime.h>

// Problem constants
constexpr int B      = 16384;
constexpr int D_IN   = 1024;
constexpr int D_OUT  = 256;
constexpr int NCLS   = 1000;

// ---------------- workspace layout (byte offsets) ----------------
constexpr size_t OFF_WB  = 0;                                   // 512*D_IN bf16    (1 MB)
constexpr size_t OFF_XB  = OFF_WB + (size_t)512 * D_IN * 2;     // B*D_IN bf16      (32 MB)
constexpr size_t OFF_V   = OFF_XB + (size_t)B * D_IN * 2;       // 1024*D_OUT f32   (1 MB, zeroed)
constexpr size_t OFF_U   = OFF_V  + (size_t)1024 * D_OUT * 4;   // D_OUT f32 (zeroed)
constexpr size_t OFF_CNT = OFF_U  + 4096;                       // 1024 int
constexpr size_t OFF_B12 = OFF_CNT + 4096;                      // D_OUT f32 (b1+b2)

typedef short bf16x8 __attribute__((ext_vector_type(8)));
typedef float f32x4  __attribute__((ext_vector_type(4)));

// fp32 -> bf16 round-to-nearest-even (bit trick; used only in tiny W-convert)
__device__ __forceinline__ unsigned short f2bf(float f) {
    unsigned int u = __float_as_uint(f);
    return (unsigned short)((u + 0x7FFFu + ((u >> 16) & 1u)) >> 16);
}

__device__ __forceinline__ void cvt8(const float4& a, const float4& b, unsigned short* dst) {
    union { unsigned short u[8]; bf16x8 v; } r;
    r.u[0] = f2bf(a.x); r.u[1] = f2bf(a.y); r.u[2] = f2bf(a.z); r.u[3] = f2bf(a.w);
    r.u[4] = f2bf(b.x); r.u[5] = f2bf(b.y); r.u[6] = f2bf(b.z); r.u[7] = f2bf(b.w);
    *(bf16x8*)dst = r.v;
}

// HW packed f32->bf16 (RNE), 1 instr per 2 floats
__device__ __forceinline__ unsigned int cvtpk(float lo, float hi) {
    unsigned int r;
    asm volatile("v_cvt_pk_bf16_f32 %0, %1, %2" : "=v"(r) : "v"(lo), "v"(hi));
    return r;
}

// async global->LDS, 16B/lane; lds dst = wave-uniform base (+lane*16 implied by HW)
__device__ __forceinline__ void async16(const unsigned short* g, unsigned short* l) {
    __builtin_amdgcn_global_load_lds(
        (const __attribute__((address_space(1))) void*)g,
        (__attribute__((address_space(3))) void*)l,
        16, 0, 0);
}

// ---- K0: blk0 = histogram + b12; blk 1..128 = W cvt; blk 129..192 = zero V,U ----
__global__ __launch_bounds__(256)
void prep_kernel(const float* __restrict__ W1, const float* __restrict__ W2,
                 const float* __restrict__ b1, const float* __restrict__ b2,
                 const int* __restrict__ label,
                 unsigned short* __restrict__ Wb,
                 float* __restrict__ V, float* __restrict__ U,
                 int* __restrict__ cnt, float* __restrict__ b12) {
    const int blk = blockIdx.x, tid = threadIdx.x;
    if (blk == 0) {
        __shared__ int h[1024];
#pragma unroll
        for (int q = 0; q < 4; ++q) h[q * 256 + tid] = 0;
        __syncthreads();
        for (int base = 0; base < 64; base += 16) {
            int lv[16];
#pragma unroll
            for (int u = 0; u < 16; ++u) lv[u] = label[(base + u) * 256 + tid];
#pragma unroll
            for (int u = 0; u < 16; ++u) atomicAdd(&h[lv[u]], 1);
        }
        __syncthreads();
#pragma unroll
        for (int q = 0; q < 4; ++q) cnt[q * 256 + tid] = h[q * 256 + tid];
        b12[tid] = b1[tid] + b2[tid];
    } else if (blk <= 128) {
        int lin = (blk - 1) * 256 + tid;
        int i = lin * 16;                              // 262144 % 16 == 0: no W1/W2 straddle
        const float* src = (i < D_OUT * D_IN) ? (W1 + i) : (W2 + (i - D_OUT * D_IN));
        float4 a0 = *(const float4*)(src);
        float4 a1 = *(const float4*)(src + 4);
        float4 a2 = *(const float4*)(src + 8);
        float4 a3 = *(const float4*)(src + 12);
        cvt8(a0, a1, Wb + i);
        cvt8(a2, a3, Wb + i + 8);
    } else {
        int lb = blk - 129;                            // 0..63
        int base = (lb * 256 + tid) * 16;
#pragma unroll
        for (int q = 0; q < 4; ++q)
            *(float4*)(V + base + q * 4) = float4{0.f, 0.f, 0.f, 0.f};
        if (lb == 0 && tid < 64)
            *(float4*)(U + tid * 4) = float4{0.f, 0.f, 0.f, 0.f};
    }
}

// ---- K1: y2 = x @ W2b^T (N=256), A cvt'd in-register; emits xb; folds V/U ----
// 128x64 tiles, BK=64, grid 512. r8 pipeline (counted vmcnt, 1 barrier/step).
// by==0 blocks also store the bf16 A-tile to xb (each bm panel written once).
__global__ __launch_bounds__(256, 2)
void gemm2_kernel(const float* __restrict__ x,
                  const unsigned short* __restrict__ Wb,
                  const int* __restrict__ label,
                  unsigned short* __restrict__ xb,
                  float* __restrict__ V, float* __restrict__ U) {
    __shared__ unsigned short As[2][128][64];   // 32 KB
    __shared__ unsigned short Bs[2][64][64];    // 16 KB

    const int tid  = threadIdx.x;
    const int bid  = blockIdx.x;
    const int xcd   = bid & 7;
    const int local = bid >> 3;              // 0..63
    const int bx = xcd * 16 + (local & 15);  // 0..127
    const int by = local >> 4;               // 0..3
    const int bm = bx * 128;
    const int bn = by * 64;                  // y2 col base in [0,256)

    const int wave = tid >> 6, lane = tid & 63;
    const int quad = lane >> 4, l16 = lane & 15;
    const int wm = (wave >> 1) * 64;
    const int wn = (wave & 1) * 32;
    const int sx = l16 & 7;

    // A: 1024 chunks (row=dd>>3, slot=dd&7), source k-col pre-swizzled
    const float* xps[4];
    unsigned short* xbp[4];
    int adst[4];
#pragma unroll
    for (int rr = 0; rr < 4; ++rr) {
        int dd = rr * 256 + tid;
        int r = dd >> 3, sl = dd & 7;
        int sc = sl ^ (r & 7);
        xps[rr] = x  + (size_t)(bm + r) * D_IN + sc * 8;
        xbp[rr] = xb + (size_t)(bm + r) * D_IN + sc * 8;
        adst[rr] = dd * 8;
    }
    // B: 512 chunks (Wb rows 256+bn .. 256+bn+63)
    const unsigned short* bps[2];
#pragma unroll
    for (int rr = 0; rr < 2; ++rr) {
        int dd = rr * 256 + tid;
        int r = dd >> 3, sl = dd & 7;
        int sc = sl ^ (r & 7);
        bps[rr] = Wb + (size_t)(256 + bn + r) * D_IN + sc * 8;
    }
    const bool emit = (by == 0);

    f32x4 acc[4][2] = {};
    float4 a0[4], a1[4];

    // ---- prologue: tile 0 ----
#pragma unroll
    for (int rr = 0; rr < 4; ++rr) {
        a0[rr] = *(const float4*)(xps[rr]);
        a1[rr] = *(const float4*)(xps[rr] + 4);
    }
#pragma unroll
    for (int rr = 0; rr < 2; ++rr)
        async16(bps[rr], &Bs[0][0][0] + rr * 2048 + wave * 512);
#pragma unroll
    for (int rr = 0; rr < 4; ++rr) {
        union { unsigned int w[4]; bf16x8 v; } p;
        p.w[0] = cvtpk(a0[rr].x, a0[rr].y);
        p.w[1] = cvtpk(a0[rr].z, a0[rr].w);
        p.w[2] = cvtpk(a1[rr].x, a1[rr].y);
        p.w[3] = cvtpk(a1[rr].z, a1[rr].w);
        *(bf16x8*)(&As[0][0][0] + adst[rr]) = p.v;
        if (emit) *(bf16x8*)(xbp[rr]) = p.v;
    }

    for (int t = 0; t < 16; ++t) {
        const int cur = t & 1;
        const int k1 = (t + 1) * 64;
        if (t < 15) {
#pragma unroll
            for (int rr = 0; rr < 4; ++rr) {
                a0[rr] = *(const float4*)(xps[rr] + k1);
                a1[rr] = *(const float4*)(xps[rr] + k1 + 4);
            }
            // outstanding: [2 B(t) (+4 xb stores)] then 8 A(t+1); vmcnt(8) drains
            // everything older than the A loads -> B(t) landed.
            asm volatile("s_waitcnt vmcnt(8)" ::: "memory");
        } else {
            asm volatile("s_waitcnt vmcnt(0)" ::: "memory");
        }
        asm volatile("s_waitcnt lgkmcnt(0)" ::: "memory");
        __builtin_amdgcn_s_barrier();
        __builtin_amdgcn_sched_barrier(0);
        if (t < 15) {
#pragma unroll
            for (int rr = 0; rr < 2; ++rr)
                async16(bps[rr] + k1, &Bs[cur ^ 1][0][0] + rr * 2048 + wave * 512);
        }

#pragma unroll
        for (int ks = 0; ks < 2; ++ks) {
            const int s = ks * 4 + quad;
            bf16x8 af[4], bfr[2];
#pragma unroll
            for (int i = 0; i < 4; ++i)
                af[i] = *(const bf16x8*)&As[cur][wm + i * 16 + l16][((s ^ sx) * 8)];
#pragma unroll
            for (int j = 0; j < 2; ++j)
                bfr[j] = *(const bf16x8*)&Bs[cur][wn + j * 16 + l16][((s ^ sx) * 8)];
#pragma unroll
            for (int i = 0; i < 4; ++i)
#pragma unroll
                for (int j = 0; j < 2; ++j)
                    acc[i][j] = __builtin_amdgcn_mfma_f32_16x16x32_bf16(af[i], bfr[j], acc[i][j], 0, 0, 0);
        }

        if (t < 15) {
#pragma unroll
            for (int rr = 0; rr < 4; ++rr) {
                union { unsigned int w[4]; bf16x8 v; } p;
                p.w[0] = cvtpk(a0[rr].x, a0[rr].y);
                p.w[1] = cvtpk(a0[rr].z, a0[rr].w);
                p.w[2] = cvtpk(a1[rr].x, a1[rr].y);
                p.w[3] = cvtpk(a1[rr].z, a1[rr].w);
                *(bf16x8*)(&As[cur ^ 1][0][0] + adst[rr]) = p.v;
                if (emit) *(bf16x8*)(xbp[rr] + k1) = p.v;
            }
        }
    }

    // fold y2 into V[label] + column-sum into U
    int lab[4][4];
#pragma unroll
    for (int i = 0; i < 4; ++i)
#pragma unroll
        for (int r = 0; r < 4; ++r)
            lab[i][r] = label[bm + wm + i * 16 + quad * 4 + r] * D_OUT;

#pragma unroll
    for (int j = 0; j < 2; ++j) {
        const int n = bn + wn + j * 16 + l16;
        float cs = 0.f;
#pragma unroll
        for (int i = 0; i < 4; ++i)
#pragma unroll
            for (int r = 0; r < 4; ++r) {
                float v = acc[i][j][r];
                cs += v;
                atomicAdd(&V[lab[i][r] + n], v);
            }
        cs += __shfl_xor(cs, 16);
        cs += __shfl_xor(cs, 32);   // sum over quads -> 64-row column sum
        if (quad == 0) atomicAdd(&U[n], cs);
    }
}

// ---- K2: out = xb @ W1b^T + b12 + (U - V[label]) * inv ; fused epilogue ----
// r7-proven pure global_load_lds loop, 128x64 tile, BK=64, 24 KB LDS, grid 512.
__global__ __launch_bounds__(256)
void gemm1_kernel(const unsigned short* __restrict__ xb,
                  const unsigned short* __restrict__ Wb,
                  const int* __restrict__ label,
                  const float* __restrict__ V, const float* __restrict__ U,
                  const int* __restrict__ cnt, const float* __restrict__ b12,
                  float* __restrict__ out) {
    __shared__ unsigned short As[128][64];   // 16 KB
    __shared__ unsigned short Bs[64][64];    //  8 KB

    const int tid  = threadIdx.x;
    const int bid  = blockIdx.x;
    const int xcd   = bid & 7;
    const int local = bid >> 3;
    const int bx = xcd * 16 + (local & 15);  // 0..127
    const int by = local >> 4;               // 0..3
    const int bm = bx * 128;
    const int bn = by * 64;                  // in [0,256)

    const int wave = tid >> 6, lane = tid & 63;
    const int quad = lane >> 4, l16 = lane & 15;
    const int wm = (wave >> 1) * 64;
    const int wn = (wave & 1) * 32;
    const int sx = l16 & 7;

    const unsigned short* aps[4];
#pragma unroll
    for (int rr = 0; rr < 4; ++rr) {
        int dd = rr * 256 + tid;
        int r = dd >> 3, sl = dd & 7;
        int sc = sl ^ (r & 7);
        aps[rr] = xb + (size_t)(bm + r) * D_IN + sc * 8;
    }
    const unsigned short* bps[2];
#pragma unroll
    for (int rr = 0; rr < 2; ++rr) {
        int dd = rr * 256 + tid;
        int r = dd >> 3, sl = dd & 7;
        int sc = sl ^ (r & 7);
        bps[rr] = Wb + (size_t)(bn + r) * D_IN + sc * 8;
    }

    f32x4 acc[4][2] = {};

    for (int k0 = 0; k0 < D_IN; k0 += 64) {
        __syncthreads();   // previous iteration's frag reads complete
#pragma unroll
        for (int rr = 0; rr < 4; ++rr)
            async16(aps[rr] + k0, &As[0][0] + rr * 2048 + wave * 512);
#pragma unroll
        for (int rr = 0; rr < 2; ++rr)
            async16(bps[rr] + k0, &Bs[0][0] + rr * 2048 + wave * 512);
        __syncthreads();   // vmcnt drain before frag reads

#pragma unroll
        for (int ks = 0; ks < 2; ++ks) {
            const int s = ks * 4 + quad;
            bf16x8 af[4], bfr[2];
#pragma unroll
            for (int i = 0; i < 4; ++i)
                af[i] = *(const bf16x8*)&As[wm + i * 16 + l16][((s ^ sx) * 8)];
#pragma unroll
            for (int j = 0; j < 2; ++j)
                bfr[j] = *(const bf16x8*)&Bs[wn + j * 16 + l16][((s ^ sx) * 8)];
#pragma unroll
            for (int i = 0; i < 4; ++i)
#pragma unroll
                for (int j = 0; j < 2; ++j)
                    acc[i][j] = __builtin_amdgcn_mfma_f32_16x16x32_bf16(af[i], bfr[j], acc[i][j], 0, 0, 0);
        }
    }

    // fused epilogue: out[m][n] = acc + b12[n] + (U[n] - V[lab[m]][n]) * inv[m]
    int lab[4][4];
    float inv[4][4];
#pragma unroll
    for (int i = 0; i < 4; ++i)
#pragma unroll
        for (int r = 0; r < 4; ++r) {
            const int m = bm + wm + i * 16 + quad * 4 + r;
            const int L = label[m];
            lab[i][r] = L * D_OUT;
            inv[i][r] = 1.0f / (float)(B - cnt[L]);
        }

#pragma unroll
    for (int j = 0; j < 2; ++j) {
        const int n = bn + wn + j * 16 + l16;
        const float un = U[n];
        const float bb = b12[n];
#pragma unroll
        for (int i = 0; i < 4; ++i)
#pragma unroll
            for (int r = 0; r < 4; ++r) {
                const int m = bm + wm + i * 16 + quad * 4 + r;
                out[(size_t)m * D_OUT + n] =
                    acc[i][j][r] + bb + (un - V[lab[i][r] + n]) * inv[i][r];
            }
    }
}

// ---------------- launcher ----------------
extern "C" void kernel_launch(void* const* d_in, const int* in_sizes, int n_in,
                              void* d_out, int out_size, void* d_ws, size_t ws_size,
                              hipStream_t stream) {
    const float* x    = (const float*)d_in[0];
    const int*   lab  = (const int*)d_in[1];
    const float* W1_w = (const float*)d_in[2];
    const float* W1_b = (const float*)d_in[3];
    const float* W2_w = (const float*)d_in[4];
    const float* W2_b = (const float*)d_in[5];
    float* out = (float*)d_out;

    char* ws = (char*)d_ws;
    unsigned short* Wb = (unsigned short*)(ws + OFF_WB);
    unsigned short* xb = (unsigned short*)(ws + OFF_XB);
    float* V   = (float*)(ws + OFF_V);
    float* U   = (float*)(ws + OFF_U);
    int*   cnt = (int*)(ws + OFF_CNT);
    float* b12 = (float*)(ws + OFF_B12);

    // K0: hist + b12 + W cvt + zero V/U (tiny)
    prep_kernel<<<193, 256, 0, stream>>>(W1_w, W2_w, W1_b, W2_b, lab, Wb, V, U, cnt, b12);
    // K1: y2 pass — converts x in-register, emits xb, folds V/U
    gemm2_kernel<<<512, 256, 0, stream>>>(x, Wb, lab, xb, V, U);
    // K2: y1 pass + fused epilogue -> out
    gemm1_kernel<<<512, 256, 0, stream>>>(xb, Wb, lab, V, U, cnt, b12, out);
}